// Round 4
// baseline (73.674 us; speedup 1.0000x reference)
//
#include <hip/hip_runtime.h>
#include <math.h>

#define NPART 2048
#define MI    2               // i-particles per thread (register tile)
#define GRP   8               // thread-groups per block (tid>>6)
#define IPB   (GRP * MI)      // 16 i-particles per block
#define BLOCK 512             // 8 waves; j-split = 64 (full wave)

#if __has_builtin(__builtin_amdgcn_rsqf)
#define RSQF(x) __builtin_amdgcn_rsqf(x)
#else
#define RSQF(x) rsqrtf(x)
#endif
#if __has_builtin(__builtin_amdgcn_exp2f)
#define EXP2F(x) __builtin_amdgcn_exp2f(x)
#else
#define EXP2F(x) exp2f(x)
#endif

// Scaled-coordinate backflow: u = x/L in [0,1).
//   min-image: du -= rint(du)
//   fr = 0.5*(exp2(K * (1/|du|)^5) - 1),  K = -log2(e)*(2.6/L)^5
//   out = L * (u_i + sum_j fr * du)
// Self-pair: d2=0 -> ri=inf -> K*ri^5=-inf -> exp2=0 -> fr=-0.5, fr*0=0. No NaN.
__global__ __launch_bounds__(BLOCK, 4)   // 128-VGPR budget: no spills, ILP covers latency
void backflow_kernel(const float* __restrict__ x, float* __restrict__ out,
                     float L, float invL, float K) {
    __shared__ float4 ps[NPART];   // 32 KB scaled positions

    const int tid   = threadIdx.x;
    const int blk   = blockIdx.x;
    const int b     = blk >> 7;             // 8 batches x 128 blocks each
    const int ibase = (blk & 127) * IPB;
    const float* xb = x + b * (NPART * 3);

    for (int p = tid; p < NPART; p += BLOCK) {
        float ux = xb[3 * p + 0] * invL;
        float uy = xb[3 * p + 1] * invL;
        float uz = xb[3 * p + 2] * invL;
        ux -= floorf(ux);
        uy -= floorf(uy);
        uz -= floorf(uz);
        ps[p] = make_float4(ux, uy, uz, 0.0f);
    }
    __syncthreads();

    const int lane = tid & 63;              // j-split across the full wave
    const int g    = tid >> 6;              // 0..7
    const int i0   = ibase + g * MI;

    const float4 pi0 = ps[i0];              // wave-uniform broadcast reads
    const float4 pi1 = ps[i0 + 1];

    float ax0 = 0.f, ay0 = 0.f, az0 = 0.f;
    float ax1 = 0.f, ay1 = 0.f, az1 = 0.f;

    #pragma unroll 2
    for (int k = 0; k < NPART / 64; ++k) {
        const int j = lane + (k << 6);
        const float4 pj = ps[j];            // 64 contiguous float4: full-BW b128, no conflicts

        // pair (i0, j)
        float dx = pi0.x - pj.x, dy = pi0.y - pj.y, dz = pi0.z - pj.z;
        dx -= rintf(dx);  dy -= rintf(dy);  dz -= rintf(dz);
        float d2  = fmaf(dx, dx, fmaf(dy, dy, dz * dz));
        float ri  = RSQF(d2);
        float ri2 = ri * ri;
        float ri4 = ri2 * ri2;
        float fr  = fmaf(0.5f, EXP2F((K * ri4) * ri), -0.5f);
        ax0 = fmaf(fr, dx, ax0); ay0 = fmaf(fr, dy, ay0); az0 = fmaf(fr, dz, az0);

        // pair (i0+1, j) — independent chain (ILP)
        float ex = pi1.x - pj.x, ey = pi1.y - pj.y, ez = pi1.z - pj.z;
        ex -= rintf(ex);  ey -= rintf(ey);  ez -= rintf(ez);
        float e2  = fmaf(ex, ex, fmaf(ey, ey, ez * ez));
        float si  = RSQF(e2);
        float si2 = si * si;
        float si4 = si2 * si2;
        float fs  = fmaf(0.5f, EXP2F((K * si4) * si), -0.5f);
        ax1 = fmaf(fs, ex, ax1); ay1 = fmaf(fs, ey, ay1); az1 = fmaf(fs, ez, az1);
    }

    // full-wave reduction (64 lanes -> lane 0), 6 accumulators
    #pragma unroll
    for (int off = 32; off >= 1; off >>= 1) {
        ax0 += __shfl_xor(ax0, off); ay0 += __shfl_xor(ay0, off); az0 += __shfl_xor(az0, off);
        ax1 += __shfl_xor(ax1, off); ay1 += __shfl_xor(ay1, off); az1 += __shfl_xor(az1, off);
    }

    if (lane == 0) {
        float* o0 = out + (b * NPART + i0) * 3;
        o0[0] = L * (pi0.x + ax0);
        o0[1] = L * (pi0.y + ay0);
        o0[2] = L * (pi0.z + az0);
        o0[3] = L * (pi1.x + ax1);
        o0[4] = L * (pi1.y + ay1);
        o0[5] = L * (pi1.z + az1);
    }
}

extern "C" void kernel_launch(void* const* d_in, const int* in_sizes, int n_in,
                              void* d_out, int out_size, void* d_ws, size_t ws_size,
                              hipStream_t stream) {
    (void)in_sizes; (void)n_in; (void)d_ws; (void)ws_size; (void)out_size;
    const float* x = (const float*)d_in[0];
    float* out     = (float*)d_out;

    const double Ld   = cbrt(2048.0 / 0.016355);
    const double t    = 2.6 / Ld;
    const double Kd   = -(t * t * t * t * t) * 1.4426950408889634;
    const float  L    = (float)Ld;
    const float  invL = (float)(1.0 / Ld);
    const float  K    = (float)Kd;

    const int nblocks = (8 * NPART) / IPB;   // 1024
    backflow_kernel<<<nblocks, BLOCK, 0, stream>>>(x, out, L, invL, K);
}